// Round 1
// baseline (108.949 us; speedup 1.0000x reference)
//
#include <hip/hip_runtime.h>

// DA-RNN (LSTM_price): T=10, D=45, H=45. fp32 in/out/compute.
// Single workgroup (256 thr), single launch, latency-optimized.
// R1 change vs previous best: eliminate the scattered per-lane row
// gathers for Whh_e (wave0: 180 scalar loads x ~45 lines) and Wih_e
// (waves1-3: 45 loads x ~60 lines x 3 waves) by staging both matrices
// COALESCED (float4) through one serially-reused 8100-float LDS region:
//   sR1 = Whh_e (t0..B1) -> Wih_e (B2..B3) -> {Wfc[0:4050], W1c[4050:6075]}
// Scattered TA line-requests drop ~24K -> ~8K (only the Wih_d row
// gather remains; its latency hides under the encoder phases).
// Algebra (verified in prior session): Wa[0:90]/ba/b2/Whh_d dead;
// input attention time-invariant; decoder c2 = sig(i)*tanh(g).

static constexpr int NT = 10;
static constexpr int ND = 45;
static constexpr int NH = 45;
static constexpr int NG = 4 * NH; // 180

__device__ __forceinline__ float rcp_(float x) { return __builtin_amdgcn_rcpf(x); }
__device__ __forceinline__ float sigf(float x) { return rcp_(1.0f + __expf(-x)); }
__device__ __forceinline__ float tanh_(float x) { return 1.0f - 2.0f * rcp_(1.0f + __expf(2.0f * x)); }

__global__ __launch_bounds__(256) void darnn_kernel(
    const float* __restrict__ X,      // [T,D]
    const float* __restrict__ Wa,     // [1,2H+T] (only [90:100] live)
    const float* __restrict__ Wih_e,  // [4H,D]
    const float* __restrict__ Whh_e,  // [4H,H]
    const float* __restrict__ bih_e,  // [4H]
    const float* __restrict__ bhh_e,  // [4H]
    const float* __restrict__ W1,     // [D,2H+D] (cols 90:135 live)
    const float* __restrict__ b1,     // [D]
    const float* __restrict__ W2,     // [1,D]
    const float* __restrict__ Wih_d,  // [4H,D]
    const float* __restrict__ bih_d,  // [4H]
    const float* __restrict__ bhh_d,  // [4H]
    const float* __restrict__ Wfc,    // [45,2H]
    const float* __restrict__ bfc,    // [45]
    float* __restrict__ out)          // [45]
{
    const int tid  = threadIdx.x;
    const int wave = tid >> 6;
    const int lane = tid & 63;
    const int g    = tid - 64;        // staging-thread gate id (waves 1-3)

    // static LDS: 12,160 floats = 48,640 B
    __shared__ float sR1[8100];       // Whh_e -> Wih_e -> {Wfc, W1c}
    __shared__ float sGx[NT * NG];    // 1800
    __shared__ float sX[NT * ND];     // 450
    __shared__ float sWi[NT * ND];    // 450
    __shared__ float shs[NT * NH];    // 450
    __shared__ float sdec[NT * NH];   // 450
    __shared__ float sattn[ND];
    __shared__ float sat[NT];
    __shared__ float sctx[NH];
    __shared__ float sh1v[NH];
    __shared__ float sg[NG];
    __shared__ float sb1[ND];
    __shared__ float sW2v[ND];
    __shared__ float sbfcv[45];

    // ---- t=0: issue ALL cold fetches ----
    float wd[45];                     // waves 1-3 (g<180): Wih_d row (gather, hidden)
    float bd = 0.0f, be = 0.0f;
    float4 re[11];                    // waves 1-3: coalesced Wih_e chunks

    { // Whh_e -> sR1, coalesced float4 (2025 chunks over 256 threads)
        const float4* src = (const float4*)Whh_e;
        float4*       dst = (float4*)sR1;
#pragma unroll
        for (int k = 0; k < 8; ++k) {
            const int i = tid + k * 256;
            if (i < 2025) dst[i] = src[i];
        }
    }
    if (wave == 0) {
        // X -> sX, coalesced float2 (225 chunks over 64 lanes)
        const float2* x2 = (const float2*)X;
        float2*       d2 = (float2*)sX;
#pragma unroll
        for (int k = 0; k < 4; ++k) {
            const int i = lane + k * 64;
            if (i < 225) d2[i] = x2[i];
        }
    } else {
        if (g < NG) {
            // Wih_d row gather (latency hidden: first use is ~8 us away)
            const float* wrD = Wih_d + g * ND;
#pragma unroll
            for (int d = 0; d < 45; ++d) wd[d] = wrD[d];
            be = bih_e[g] + bhh_e[g];
            bd = bih_d[g] + bhh_d[g];
        }
        // Wih_e coalesced into registers (written to sR1 after B1)
        {
            const float4* src = (const float4*)Wih_e;
            const int s = tid - 64; // 0..191
#pragma unroll
            for (int k = 0; k < 11; ++k) {
                const int i = s + k * 192;
                if (i < 2025) re[k] = src[i];
            }
        }
    }
    __syncthreads(); // B0: sR1 = Whh_e, sX ready

    // ---- B0->B1: wave0 stages Whh rows from LDS; wave1 runs attention ----
    float w0[45], w1[45], w2[45], w3[45];
    if (wave == 0) {
        const int j = (lane < 45) ? lane : 0; // lanes 45-63 duplicate row 0
#pragma unroll
        for (int k = 0; k < 45; ++k) {
            w0[k] = sR1[j * 45 + k];
            w1[k] = sR1[(45 + j) * 45 + k];
            w2[k] = sR1[(90 + j) * 45 + k];
            w3[k] = sR1[(135 + j) * 45 + k];
        }
    } else if (wave == 1) {
        // input attention (time-invariant) + sWi
        float acc = -1e30f;
        if (lane < ND) {
            acc = 0.0f;
            for (int t = 0; t < NT; ++t) acc += Wa[90 + t] * sX[t * ND + lane];
        }
        float m = acc;
        for (int off = 32; off; off >>= 1) m = fmaxf(m, __shfl_xor(m, off, 64));
        float e = (lane < ND) ? __expf(acc - m) : 0.0f;
        float s = e;
        for (int off = 32; off; off >>= 1) s += __shfl_xor(s, off, 64);
        if (lane < ND) sattn[lane] = e * rcp_(s);
        __builtin_amdgcn_s_waitcnt(0);      // sattn visible within the wave
        __builtin_amdgcn_wave_barrier();
        for (int i = lane; i < NT * ND; i += 64) sWi[i] = sattn[i % ND] * sX[i];
    }
    __syncthreads(); // B1: sR1 free (wave0 done), sWi ready

    // ---- waves 1-3: Wih_e registers -> sR1 ----
    if (wave > 0) {
        float4* dst = (float4*)sR1;
        const int s = tid - 64;
#pragma unroll
        for (int k = 0; k < 11; ++k) {
            const int i = s + k * 192;
            if (i < 2025) dst[i] = re[k];
        }
    }
    __syncthreads(); // B2: sR1 = Wih_e

    // ---- Gx[t][g]: input-half of encoder gates ----
    if (wave > 0 && g < NG) {
        float we[45];
#pragma unroll
        for (int d = 0; d < 45; ++d) we[d] = sR1[g * 45 + d]; // 2-way banks, free
        float acc[NT];
#pragma unroll
        for (int t = 0; t < NT; ++t) acc[t] = be;
        for (int d = 0; d < ND; ++d) {
            const float wv = we[d];
#pragma unroll
            for (int t = 0; t < NT; ++t) acc[t] += wv * sWi[t * ND + d];
        }
#pragma unroll
        for (int t = 0; t < NT; ++t) sGx[t * NG + g] = acc[t];
    }
    __syncthreads(); // B3: sGx ready, sR1 free again

    // ---- FORK: wave 0 serial recurrence; waves 1-3 stage decoder LDS ----
    if (wave == 0) {
        const int j = (lane < 45) ? lane : 0;
        float h = 0.0f, c = 0.0f;
        for (int t = 0; t < NT; ++t) {
            float a0 = sGx[t * NG + j];
            float a1 = sGx[t * NG + 45 + j];
            float a2 = sGx[t * NG + 90 + j];
            float a3 = sGx[t * NG + 135 + j];
#pragma unroll
            for (int k = 0; k < 45; ++k) {
                const float hk = __shfl(h, k, 64);
                a0 += w0[k] * hk; a1 += w1[k] * hk;
                a2 += w2[k] * hk; a3 += w3[k] * hk;
            }
            c = sigf(a1) * c + sigf(a0) * tanh_(a2);
            h = sigf(a3) * tanh_(c);
            if (lane < 45) shs[t * NH + lane] = h;
        }
    } else {
        const int i0 = tid - 64; // 0..191
        { // Wfc -> sR1[0:4050]: 2025 float2, coalesced
            const float2* s2 = (const float2*)Wfc;
            float2* d2 = (float2*)sR1;
            for (int i = i0; i < 2025; i += 192) d2[i] = s2[i];
        }
        // W1 live columns (90:135 of each 135-wide row) -> sR1[4050:6075]
        for (int i = i0; i < ND * ND; i += 192) {
            const int r = i / 45, cc = i - r * 45;
            sR1[4050 + i] = W1[r * 135 + 90 + cc];
        }
        if (i0 < 45) { sb1[i0] = b1[i0]; sW2v[i0] = W2[i0]; sbfcv[i0] = bfc[i0]; }
    }
    __syncthreads(); // B4

    // ---- decoder temporal attention ----
    for (int i = tid; i < NT * NH; i += 256) {
        const int t = i / NH, k = i - t * NH;
        const float* wr = sR1 + 4050 + k * ND;
        const float* hv = shs + t * NH;
        float a = sb1[k];
        for (int jj = 0; jj < ND; ++jj) a += wr[jj] * hv[jj];
        sdec[i] = sW2v[k] * tanh_(a);
    }
    __syncthreads();

    if (tid < NT) {
        float a = 0.0f;
        for (int k = 0; k < NH; ++k) a += sdec[tid * NH + k];
        sat[tid] = a; // b2 cancels in softmax
    }
    __syncthreads();
    if (tid == 0) {
        float m = -1e30f;
        for (int t = 0; t < NT; ++t) m = fmaxf(m, sat[t]);
        float e[NT], s = 0.0f;
        for (int t = 0; t < NT; ++t) { e[t] = __expf(sat[t] - m); s += e[t]; }
        const float inv = rcp_(s);
        for (int t = 0; t < NT; ++t) sat[t] = e[t] * inv;
    }
    __syncthreads();

    if (tid < NH) {
        float a = 0.0f;
        for (int t = 0; t < NT; ++t) a += sat[t] * shs[t * NH + tid];
        sctx[tid] = a;
    }
    __syncthreads();

    // ---- decoder LSTM (h=c=0): gate g from registers held since t=0 ----
    if (wave > 0 && g < NG) {
        float a = bd;
#pragma unroll
        for (int d = 0; d < 45; ++d) a += wd[d] * sctx[d];
        sg[g] = a;
    }
    __syncthreads();
    if (tid < NH) {
        const float ig = sigf(sg[tid]);
        const float gg = tanh_(sg[2 * NH + tid]);
        const float og = sigf(sg[3 * NH + tid]);
        sh1v[tid] = og * tanh_(ig * gg); // c0 = 0
    }
    __syncthreads();

    // ---- final fc: y = [h1, ctx] @ Wfc.T + bfc ----
    if (tid < 45) {
        const float* wr = sR1 + tid * (2 * NH);
        float a = sbfcv[tid];
        for (int jj = 0; jj < NH; ++jj) a += wr[jj] * sh1v[jj];
        for (int jj = 0; jj < NH; ++jj) a += wr[NH + jj] * sctx[jj];
        out[tid] = a;
    }
}

extern "C" void kernel_launch(void* const* d_in, const int* in_sizes, int n_in,
                              void* d_out, int out_size, void* d_ws, size_t ws_size,
                              hipStream_t stream) {
    const float* X     = (const float*)d_in[0];
    const float* Wa    = (const float*)d_in[1];
    // d_in[2] = ba — dead
    const float* Wih_e = (const float*)d_in[3];
    const float* Whh_e = (const float*)d_in[4];
    const float* bih_e = (const float*)d_in[5];
    const float* bhh_e = (const float*)d_in[6];
    const float* W1    = (const float*)d_in[7];
    const float* b1    = (const float*)d_in[8];
    const float* W2    = (const float*)d_in[9];
    // d_in[10] = b2 — dead
    const float* Wih_d = (const float*)d_in[11];
    // d_in[12] = Whh_d — dead
    const float* bih_d = (const float*)d_in[13];
    const float* bhh_d = (const float*)d_in[14];
    const float* Wfc   = (const float*)d_in[15];
    const float* bfc   = (const float*)d_in[16];
    float* out = (float*)d_out;

    darnn_kernel<<<dim3(1), dim3(256), 0, stream>>>(
        X, Wa, Wih_e, Whh_e, bih_e, bhh_e, W1, b1, W2,
        Wih_d, bih_d, bhh_d, Wfc, bfc, out);
}

// Round 3
// 103.011 us; speedup vs baseline: 1.0576x; 1.0576x over previous
//
#include <hip/hip_runtime.h>

// DA-RNN (LSTM_price): T=10, D=45, H=45. fp32 in/out/compute.
// Single workgroup (256 thr), single launch, latency-optimized:
//  - ALL cold global loads issued at t=0: wave 0 prefetches Whh_e into
//    180 VGPRs; each of 180 staging threads (waves 1-3) prefetches its
//    Wih_e row AND Wih_d row (+fused biases) into registers; waves 2-3
//    stage X into LDS concurrently. Fetch latency overlaps the
//    attention preamble instead of serializing after barriers.
//  - 10-step recurrence on wave 0: pure VALU + v_readlane (__shfl),
//    no LDS traffic, no barriers inside the loop.
//  - waves 1-3 stage Wfc / W1-live-cols during the chain (hidden).
// R3 note: resubmission of the best-measured structure (R0, 105.6 us;
// prior session 103.4 us). R2's bench was an infra failure (container
// acquisition), not a kernel failure. R1 established that coalescing
// the t0 gathers through LDS regresses (+3.3 us): the scattered
// prefetches are latency-hidden; extra barriers are not.
// Algebra (verified, rounds 3/5 passed): Wa[0:90]/ba/b2/Whh_d dead;
// input attention time-invariant; decoder c2 = sig(i)*tanh(g).

static constexpr int NT = 10;
static constexpr int ND = 45;
static constexpr int NH = 45;
static constexpr int NG = 4 * NH; // 180

__device__ __forceinline__ float rcp_(float x) { return __builtin_amdgcn_rcpf(x); }
__device__ __forceinline__ float sigf(float x) { return rcp_(1.0f + __expf(-x)); }
__device__ __forceinline__ float tanh_(float x) { return 1.0f - 2.0f * rcp_(1.0f + __expf(2.0f * x)); }

__global__ __launch_bounds__(256) void darnn_kernel(
    const float* __restrict__ X,      // [T,D]
    const float* __restrict__ Wa,     // [1,2H+T] (only [90:100] live)
    const float* __restrict__ Wih_e,  // [4H,D]
    const float* __restrict__ Whh_e,  // [4H,H]
    const float* __restrict__ bih_e,  // [4H]
    const float* __restrict__ bhh_e,  // [4H]
    const float* __restrict__ W1,     // [D,2H+D] (cols 90:135 live)
    const float* __restrict__ b1,     // [D]
    const float* __restrict__ W2,     // [1,D]
    const float* __restrict__ Wih_d,  // [4H,D]
    const float* __restrict__ bih_d,  // [4H]
    const float* __restrict__ bhh_d,  // [4H]
    const float* __restrict__ Wfc,    // [45,2H]
    const float* __restrict__ bfc,    // [45]
    float* __restrict__ out)          // [45]
{
    const int tid  = threadIdx.x;
    const int wave = tid >> 6;
    const int lane = tid & 63;
    const int g    = tid - 64;        // staging-thread gate id (waves 1-3)

    // static LDS total: 10,135 floats = 40,540 B (< 64 KB static limit)
    __shared__ float sX[NT * ND];
    __shared__ float sattn[ND];
    __shared__ float sWi[NT * ND];
    __shared__ float sGx[NT * NG];
    __shared__ float shs[NT * NH];
    __shared__ float sW1c[ND * ND];
    __shared__ float sWfc[45 * 2 * NH];
    __shared__ float sb1[ND];
    __shared__ float sW2v[ND];
    __shared__ float sbfcv[45];
    __shared__ float sat[NT];
    __shared__ float sctx[NH];
    __shared__ float sh1v[NH];
    __shared__ float sg[NG];
    __shared__ float sdec[NT * NH];

    // ---- t=0: issue ALL cold fetches ----
    float w0[45], w1[45], w2[45], w3[45]; // wave 0: Whh_e
    float we[45], wd[45];                 // waves 1-3 (g<180): Wih_e / Wih_d rows
    float be = 0.0f, bd = 0.0f;
    if (wave == 0) {
        const int j = (lane < 45) ? lane : 0; // lanes 45-63 duplicate row 0
        const float* r0 = Whh_e + (j)       * NH;
        const float* r1 = Whh_e + (45 + j)  * NH;
        const float* r2 = Whh_e + (90 + j)  * NH;
        const float* r3 = Whh_e + (135 + j) * NH;
#pragma unroll
        for (int k = 0; k < 45; ++k) {
            w0[k] = r0[k]; w1[k] = r1[k]; w2[k] = r2[k]; w3[k] = r3[k];
        }
    } else {
        if (g < NG) {
            const float* wrE = Wih_e + g * ND;
            const float* wrD = Wih_d + g * ND;
#pragma unroll
            for (int d = 0; d < 45; ++d) { we[d] = wrE[d]; wd[d] = wrD[d]; }
            be = bih_e[g] + bhh_e[g];
            bd = bih_d[g] + bhh_d[g];
        }
        if (wave >= 2)
            for (int i = tid - 128; i < NT * ND; i += 128) sX[i] = X[i];
    }
    __syncthreads(); // B0: sX ready

    // ---- input attention (time-invariant) + sWi, wave 1 only ----
    if (wave == 1) {
        float acc = -1e30f;
        if (lane < ND) {
            acc = 0.0f;
            for (int t = 0; t < NT; ++t) acc += Wa[90 + t] * sX[t * ND + lane];
        }
        float m = acc;
        for (int off = 32; off; off >>= 1) m = fmaxf(m, __shfl_xor(m, off, 64));
        float e = (lane < ND) ? __expf(acc - m) : 0.0f;
        float s = e;
        for (int off = 32; off; off >>= 1) s += __shfl_xor(s, off, 64);
        if (lane < ND) sattn[lane] = e * rcp_(s);
        __builtin_amdgcn_s_waitcnt(0);      // sattn visible within the wave
        __builtin_amdgcn_wave_barrier();
        for (int i = lane; i < NT * ND; i += 64) sWi[i] = sattn[i % ND] * sX[i];
    }
    __syncthreads(); // B1: sWi ready

    // ---- Gx[t][g]: input-half of encoder gates (weights already in regs) ----
    if (wave > 0 && g < NG) {
        float acc[NT];
#pragma unroll
        for (int t = 0; t < NT; ++t) acc[t] = be;
        for (int d = 0; d < ND; ++d) {
            const float wv = we[d];
#pragma unroll
            for (int t = 0; t < NT; ++t) acc[t] += wv * sWi[t * ND + d];
        }
#pragma unroll
        for (int t = 0; t < NT; ++t) sGx[t * NG + g] = acc[t];
    }
    __syncthreads(); // B2: sGx ready

    // ---- FORK: wave 0 serial recurrence; waves 1-3 stage decoder LDS ----
    if (wave == 0) {
        const int j = (lane < 45) ? lane : 0;
        float h = 0.0f, c = 0.0f;
        for (int t = 0; t < NT; ++t) {
            float a0 = sGx[t * NG + j];
            float a1 = sGx[t * NG + 45 + j];
            float a2 = sGx[t * NG + 90 + j];
            float a3 = sGx[t * NG + 135 + j];
#pragma unroll
            for (int k = 0; k < 45; ++k) {
                const float hk = __shfl(h, k, 64);
                a0 += w0[k] * hk; a1 += w1[k] * hk;
                a2 += w2[k] * hk; a3 += w3[k] * hk;
            }
            c = sigf(a1) * c + sigf(a0) * tanh_(a2);
            h = sigf(a3) * tanh_(c);
            if (lane < 45) shs[t * NH + lane] = h;
        }
    } else {
        const int i0 = tid - 64; // 0..191
        { // Wfc: 4050 floats = 2025 float2, coalesced
            const float2* s2 = (const float2*)Wfc;
            float2* d2 = (float2*)sWfc;
            for (int i = i0; i < 2025; i += 192) d2[i] = s2[i];
        }
        // W1 live columns (90:135 of each 135-wide row)
        for (int i = i0; i < ND * ND; i += 192) {
            const int r = i / 45, cc = i - r * 45;
            sW1c[i] = W1[r * 135 + 90 + cc];
        }
        if (i0 < 45) { sb1[i0] = b1[i0]; sW2v[i0] = W2[i0]; sbfcv[i0] = bfc[i0]; }
    }
    __syncthreads(); // B3

    // ---- decoder temporal attention ----
    for (int i = tid; i < NT * NH; i += 256) {
        const int t = i / NH, k = i - t * NH;
        const float* wr = sW1c + k * ND;
        const float* hv = shs + t * NH;
        float a = sb1[k];
        for (int jj = 0; jj < ND; ++jj) a += wr[jj] * hv[jj];
        sdec[i] = sW2v[k] * tanh_(a);
    }
    __syncthreads();

    if (tid < NT) {
        float a = 0.0f;
        for (int k = 0; k < NH; ++k) a += sdec[tid * NH + k];
        sat[tid] = a; // b2 cancels in softmax
    }
    __syncthreads();
    if (tid == 0) {
        float m = -1e30f;
        for (int t = 0; t < NT; ++t) m = fmaxf(m, sat[t]);
        float e[NT], s = 0.0f;
        for (int t = 0; t < NT; ++t) { e[t] = __expf(sat[t] - m); s += e[t]; }
        const float inv = rcp_(s);
        for (int t = 0; t < NT; ++t) sat[t] = e[t] * inv;
    }
    __syncthreads();

    if (tid < NH) {
        float a = 0.0f;
        for (int t = 0; t < NT; ++t) a += sat[t] * shs[t * NH + tid];
        sctx[tid] = a;
    }
    __syncthreads();

    // ---- decoder LSTM (h=c=0): gate g from registers held since t=0 ----
    if (wave > 0 && g < NG) {
        float a = bd;
#pragma unroll
        for (int d = 0; d < 45; ++d) a += wd[d] * sctx[d];
        sg[g] = a;
    }
    __syncthreads();
    if (tid < NH) {
        const float ig = sigf(sg[tid]);
        const float gg = tanh_(sg[2 * NH + tid]);
        const float og = sigf(sg[3 * NH + tid]);
        sh1v[tid] = og * tanh_(ig * gg); // c0 = 0
    }
    __syncthreads();

    // ---- final fc: y = [h1, ctx] @ Wfc.T + bfc ----
    if (tid < 45) {
        const float* wr = sWfc + tid * (2 * NH);
        float a = sbfcv[tid];
        for (int jj = 0; jj < NH; ++jj) a += wr[jj] * sh1v[jj];
        for (int jj = 0; jj < NH; ++jj) a += wr[NH + jj] * sctx[jj];
        out[tid] = a;
    }
}

extern "C" void kernel_launch(void* const* d_in, const int* in_sizes, int n_in,
                              void* d_out, int out_size, void* d_ws, size_t ws_size,
                              hipStream_t stream) {
    const float* X     = (const float*)d_in[0];
    const float* Wa    = (const float*)d_in[1];
    // d_in[2] = ba — dead
    const float* Wih_e = (const float*)d_in[3];
    const float* Whh_e = (const float*)d_in[4];
    const float* bih_e = (const float*)d_in[5];
    const float* bhh_e = (const float*)d_in[6];
    const float* W1    = (const float*)d_in[7];
    const float* b1    = (const float*)d_in[8];
    const float* W2    = (const float*)d_in[9];
    // d_in[10] = b2 — dead
    const float* Wih_d = (const float*)d_in[11];
    // d_in[12] = Whh_d — dead
    const float* bih_d = (const float*)d_in[13];
    const float* bhh_d = (const float*)d_in[14];
    const float* Wfc   = (const float*)d_in[15];
    const float* bfc   = (const float*)d_in[16];
    float* out = (float*)d_out;

    darnn_kernel<<<dim3(1), dim3(256), 0, stream>>>(
        X, Wa, Wih_e, Whh_e, bih_e, bhh_e, W1, b1, W2,
        Wih_d, bih_d, bhh_d, Wfc, bfc, out);
}